// Round 3
// baseline (689.365 us; speedup 1.0000x reference)
//
#include <hip/hip_runtime.h>
#include <type_traits>
#include <utility>

typedef unsigned short u16;
typedef unsigned int u32;
typedef __attribute__((ext_vector_type(8))) short short8;
typedef __attribute__((ext_vector_type(8))) __bf16 bhalf8;
typedef __attribute__((ext_vector_type(4))) float f32x4;
typedef __attribute__((ext_vector_type(4))) unsigned short us4;

#define S_LEN 2048
#define NHEAD 32
#define HD 80
#define HDP 96
#define HID 2560
#define N3 7680
#define QK_SCALE 0.11180339887498949f  // 80^-0.5

// ---------- MFMA wrapper (hedge: builtin may take __bf16x8 or shortx8) ----------
template <typename T, typename = void> struct MfmaTakes : std::false_type {};
template <typename T>
struct MfmaTakes<T, std::void_t<decltype(__builtin_amdgcn_mfma_f32_16x16x32_bf16(
                       std::declval<T>(), std::declval<T>(), std::declval<f32x4>(), 0, 0, 0))>>
    : std::true_type {};

template <typename AB>
__device__ inline f32x4 mfma_raw(AB a, AB b, f32x4 c) {
  return __builtin_amdgcn_mfma_f32_16x16x32_bf16(a, b, c, 0, 0, 0);
}
using mfma_ab_t = std::conditional_t<MfmaTakes<bhalf8>::value, bhalf8, short8>;
__device__ inline f32x4 MFMA(short8 a, short8 b, f32x4 c) {
  return mfma_raw<mfma_ab_t>(__builtin_bit_cast(mfma_ab_t, a),
                             __builtin_bit_cast(mfma_ab_t, b), c);
}

__device__ inline float bf2f(u16 b) { return __uint_as_float(((u32)b) << 16); }
__device__ inline u16 f2bf(float f) {
  u32 u = __float_as_uint(f);
  u += 0x7fffu + ((u >> 16) & 1u);  // round-to-nearest-even
  return (u16)(u >> 16);
}

typedef __attribute__((address_space(1))) void as1_void;
typedef __attribute__((address_space(3))) void as3_void;

#if defined(__has_builtin)
#if __has_builtin(__builtin_amdgcn_global_load_lds)
#define HAVE_GLL 1
#endif
#endif

// Stage 16B/lane: global (per-lane addr) -> LDS (wave-uniform base + lane*16).
__device__ inline void stage16(const u16* g, u16* lds_base, int lane) {
#ifdef HAVE_GLL
  (void)lane;
  __builtin_amdgcn_global_load_lds((as1_void*)g, (as3_void*)lds_base, 16, 0, 0);
#else
  *(short8*)(lds_base + lane * 8) = *(const short8*)g;
#endif
}

// ---------- dtype detection: are the float tensors f32 or bf16 on device? ----------
// Reads first 2048 u32 words of hidden_states. If underlying data is f32, the low
// u16 of each word is float mantissa bits -> as bf16 a ~uniform-random exponent:
// ~46% have |x| >= 2^10. If underlying is bf16 (N(0,1) data), none do.
__global__ __launch_bounds__(256) void detect_dtype(const u32* __restrict__ words,
                                                    int* __restrict__ flag) {
  __shared__ int red[256];
  int junk = 0;
  for (int i = threadIdx.x; i < 2048; i += 256) {
    u16 lo = (u16)(words[i] & 0xffffu);
    u32 e = (lo >> 7) & 0xffu;  // bf16 exponent field
    junk += (e >= 137u);        // |x| >= 1024, or NaN/Inf
  }
  red[threadIdx.x] = junk;
  __syncthreads();
  for (int s = 128; s > 0; s >>= 1) {
    if (threadIdx.x < s) red[threadIdx.x] += red[threadIdx.x + s];
    __syncthreads();
  }
  if (threadIdx.x == 0) flag[0] = (red[0] > 64) ? 1 : 0;  // 1 = f32, 0 = bf16
}

// ---------- hidden_states -> bf16 (contiguous) ----------
__global__ __launch_bounds__(256) void convert_hidden(const void* __restrict__ in,
                                                      u16* __restrict__ out, int n4,
                                                      const int* __restrict__ flagp) {
  const int f = *flagp;
  int i = blockIdx.x * 256 + threadIdx.x;
  if (i >= n4) return;
  if (f) {
    const float* inf = (const float*)in;
    us4 o;
#pragma unroll
    for (int j = 0; j < 4; ++j) o[j] = f2bf(inf[(size_t)i * 4 + j]);
    *(us4*)&out[(size_t)i * 4] = o;
  } else {
    *(us4*)&out[(size_t)i * 4] = *(const us4*)&((const u16*)in)[(size_t)i * 4];
  }
}

// ---------- transpose + convert: in [rows, cols] (f32 or bf16) -> out [cols, rows] bf16 ----------
__global__ __launch_bounds__(256) void transpose_conv(const void* __restrict__ in,
                                                      u16* __restrict__ out,
                                                      int rows, int cols,
                                                      const int* __restrict__ flagp) {
  __shared__ u16 tile[32][33];
  const int f = *flagp;
  int bx = blockIdx.x * 32;  // col base
  int by = blockIdx.y * 32;  // row base
  int tx = threadIdx.x & 31, ty = threadIdx.x >> 5;
#pragma unroll
  for (int i = ty; i < 32; i += 8) {
    size_t idx = (size_t)(by + i) * cols + bx + tx;
    tile[i][tx] = f ? f2bf(((const float*)in)[idx]) : ((const u16*)in)[idx];
  }
  __syncthreads();
#pragma unroll
  for (int i = ty; i < 32; i += 8)
    out[(size_t)(bx + i) * rows + by + tx] = tile[tx][i];
}

// ---------- GEMM: A[M,K] bf16 * Bt[N,K] bf16 -> C[M,N] (fp32 accum) ----------
// m97-style: 128x128 tile, BK=32, 4 waves each 64x64, global_load_lds width 16.
// Output dtype: bf16 if (flagp==nullptr || *flagp==0), else f32.
__global__ __launch_bounds__(256) void gemm_bt(const u16* __restrict__ A,
                                               const u16* __restrict__ Bt,
                                               void* __restrict__ C,
                                               int M, int N, int K,
                                               const int* __restrict__ flagp) {
  __shared__ u16 As[128 * 32];
  __shared__ u16 Bs[128 * 32];
  const int tid = threadIdx.x;
  const int w = tid >> 6, l = tid & 63;
  const int la = l & 15, qd = l >> 4;
  const int m0 = blockIdx.y * 128, n0 = blockIdx.x * 128;
  const int mw = (w >> 1) * 64, nw = (w & 1) * 64;
  const int rowA = l >> 2;          // 0..15 within a 16-row staging slab
  const int segk = (l & 3) * 8;     // element offset within BK=32
  const int of32 = flagp ? *flagp : 0;
  f32x4 acc[4][4] = {};

  for (int k0 = 0; k0 < K; k0 += 32) {
#pragma unroll
    for (int j = 0; j < 2; ++j) {
      const int rb = w * 16 + j * 64;  // waves cover rows {0..63} then {64..127}
      const u16* ga = A + (size_t)(m0 + rb + rowA) * K + k0 + segk;
      const u16* gb = Bt + (size_t)(n0 + rb + rowA) * K + k0 + segk;
      stage16(ga, &As[rb * 32], l);
      stage16(gb, &Bs[rb * 32], l);
    }
    __syncthreads();  // drains vmcnt -> LDS visible
    short8 af[4], bfr[4];
#pragma unroll
    for (int i = 0; i < 4; ++i)
      af[i] = *(const short8*)&As[(mw + i * 16 + la) * 32 + qd * 8];
#pragma unroll
    for (int j = 0; j < 4; ++j)
      bfr[j] = *(const short8*)&Bs[(nw + j * 16 + la) * 32 + qd * 8];
#pragma unroll
    for (int i = 0; i < 4; ++i)
#pragma unroll
      for (int j = 0; j < 4; ++j)
        acc[i][j] = MFMA(af[i], bfr[j], acc[i][j]);
    __syncthreads();  // protect LDS before next overwrite
  }

#pragma unroll
  for (int i = 0; i < 4; ++i)
#pragma unroll
    for (int j = 0; j < 4; ++j) {
      const int r0 = m0 + mw + i * 16 + qd * 4;
      const int c0 = n0 + nw + j * 16 + la;
#pragma unroll
      for (int r = 0; r < 4; ++r) {
        if (of32)
          ((float*)C)[(size_t)(r0 + r) * N + c0] = acc[i][j][r];
        else
          ((u16*)C)[(size_t)(r0 + r) * N + c0] = f2bf(acc[i][j][r]);
      }
    }
}

// ---------- RoPE prep: qkv[S,7680] -> Qh/Kh [NH][S][96] (bf16, zero-padded) ----------
__global__ __launch_bounds__(256) void rope_prep(const u16* __restrict__ qkv,
                                                 const int* __restrict__ pos,
                                                 u16* __restrict__ Qh,
                                                 u16* __restrict__ Kh) {
  const int s = blockIdx.x;
  const int h = blockIdx.y * 4 + (threadIdx.x >> 6);
  const int t = threadIdx.x & 63;
  const size_t qin = (size_t)s * N3 + h * HD;
  const size_t kin = qin + HID;
  const size_t ob = ((size_t)h * S_LEN + s) * HDP;
  if (t < 32) {
    const float p = (float)pos[s];
    // inv_freq = 10000^(-t/32) = 2^(-t/32 * log2(10000))
    const float inv = exp2f(-(float)t * (13.287712379549449f / 32.0f));
    const float ang = p * inv;
    const float cs = cosf(ang), sn = sinf(ang);
    float x1 = bf2f(qkv[qin + t]), x2 = bf2f(qkv[qin + t + 32]);
    Qh[ob + t] = f2bf(x1 * cs - x2 * sn);
    Qh[ob + t + 32] = f2bf(x2 * cs + x1 * sn);
    x1 = bf2f(qkv[kin + t]);
    x2 = bf2f(qkv[kin + t + 32]);
    Kh[ob + t] = f2bf(x1 * cs - x2 * sn);
    Kh[ob + t + 32] = f2bf(x2 * cs + x1 * sn);
  } else if (t < 48) {
    const int d = t + 32;  // 64..79 pass-through
    Qh[ob + d] = qkv[qin + d];
    Kh[ob + d] = qkv[kin + d];
  } else {
    const int d = t + 32;  // 80..95 zero pad
    Qh[ob + d] = 0;
    Kh[ob + d] = 0;
  }
}

// ---------- Fused causal+ALiBi flash attention ----------
// Block = (head, 64 q rows); 4 waves x 16 rows. K-tile = 32.
__global__ __launch_bounds__(256) void attn_fused(const u16* __restrict__ Qh,
                                                  const u16* __restrict__ Kh,
                                                  const u16* __restrict__ qkv,
                                                  const int* __restrict__ pos,
                                                  u16* __restrict__ AO) {
  __shared__ u16 Vt[HD * 48];      // V^T tile: [d=80][k=32], row stride 48 (16B-aligned)
  __shared__ u16 Pl[4 * 16 * 56];  // per-wave P tile [16][32], row stride 56
  __shared__ int poskl[32];
  const int tid = threadIdx.x, w = tid >> 6, l = tid & 63;
  const int la = l & 15, qd = l >> 4;
  const int h = blockIdx.y, q0 = blockIdx.x * 64;
  const int qb = q0 + w * 16;

  short8 aq[3];
#pragma unroll
  for (int c = 0; c < 3; ++c)
    aq[c] = *(const short8*)&Qh[((size_t)h * S_LEN + qb + la) * HDP + c * 32 + qd * 8];

  const float slope = exp2f(-0.25f * (float)(h + 1));
  float posq[4];
#pragma unroll
  for (int r = 0; r < 4; ++r) posq[r] = (float)pos[qb + qd * 4 + r];

  float mr[4] = {-1e30f, -1e30f, -1e30f, -1e30f};
  float lr[4] = {0.f, 0.f, 0.f, 0.f};
  f32x4 acc[5] = {};
  u16* Pme = &Pl[w * 896];
  const int kend = q0 + 64;  // causal bound (positions are arange)

  for (int k0 = 0; k0 < kend; k0 += 32) {
    __syncthreads();  // previous iter done reading Vt
    // stage V^T (V read from qkv buffer, v block at col 5120)
    for (int c = tid; c < 320; c += 256) {
      const int kk = c / 10, seg = c - kk * 10;
      const u16* src = qkv + (size_t)(k0 + kk) * N3 + 2 * HID + h * HD + seg * 8;
      short8 vv = *(const short8*)src;
#pragma unroll
      for (int j = 0; j < 8; ++j) Vt[(seg * 8 + j) * 48 + kk] = (u16)vv[j];
    }
    if (tid < 32) poskl[tid] = pos[k0 + tid];
    __syncthreads();

    // QK^T: 16x32 scores per wave, 2 col-subtiles x 3 d-chunks
    f32x4 sc[2];
#pragma unroll
    for (int ct = 0; ct < 2; ++ct) {
      f32x4 z = {};
#pragma unroll
      for (int c = 0; c < 3; ++c) {
        short8 bk = *(const short8*)&Kh[((size_t)h * S_LEN + k0 + ct * 16 + la) * HDP +
                                        c * 32 + qd * 8];
        z = MFMA(aq[c], bk, z);
      }
      sc[ct] = z;
    }

    // scale + ALiBi + causal mask (masked = -1e9 exactly, matching reference)
    const float pk0 = (float)poskl[la], pk1 = (float)poskl[16 + la];
#pragma unroll
    for (int r = 0; r < 4; ++r) {
      const float rel0 = pk0 - posq[r];
      const float rel1 = pk1 - posq[r];
      sc[0][r] = (rel0 <= 0.f) ? sc[0][r] * QK_SCALE + slope * rel0 : -1e9f;
      sc[1][r] = (rel1 <= 0.f) ? sc[1][r] * QK_SCALE + slope * rel1 : -1e9f;
    }

    // online softmax (row stats replicated across the 16 lanes of each quad)
#pragma unroll
    for (int r = 0; r < 4; ++r) {
      float mx = fmaxf(sc[0][r], sc[1][r]);
      mx = fmaxf(mx, __shfl_xor(mx, 1));
      mx = fmaxf(mx, __shfl_xor(mx, 2));
      mx = fmaxf(mx, __shfl_xor(mx, 4));
      mx = fmaxf(mx, __shfl_xor(mx, 8));
      const float nm = fmaxf(mr[r], mx);
      const float al = expf(mr[r] - nm);
      const float p0 = expf(sc[0][r] - nm);
      const float p1 = expf(sc[1][r] - nm);
      sc[0][r] = p0;
      sc[1][r] = p1;
      float ps = p0 + p1;
      ps += __shfl_xor(ps, 1);
      ps += __shfl_xor(ps, 2);
      ps += __shfl_xor(ps, 4);
      ps += __shfl_xor(ps, 8);
      lr[r] = lr[r] * al + ps;
      mr[r] = nm;
#pragma unroll
      for (int dt = 0; dt < 5; ++dt) acc[dt][r] *= al;
    }

    // P: C-layout -> LDS -> A-layout (per-wave region, no barrier needed)
#pragma unroll
    for (int r = 0; r < 4; ++r) {
      Pme[(qd * 4 + r) * 56 + la] = f2bf(sc[0][r]);
      Pme[(qd * 4 + r) * 56 + 16 + la] = f2bf(sc[1][r]);
    }
    const short8 ap = *(const short8*)&Pme[la * 56 + qd * 8];
#pragma unroll
    for (int dt = 0; dt < 5; ++dt) {
      short8 bv = *(const short8*)&Vt[(dt * 16 + la) * 48 + qd * 8];
      acc[dt] = MFMA(ap, bv, acc[dt]);
    }
  }

  // epilogue: normalize, write attn_out [S][2560] bf16
#pragma unroll
  for (int r = 0; r < 4; ++r) {
    const float inv = 1.0f / lr[r];
    const int row = qb + qd * 4 + r;
#pragma unroll
    for (int dt = 0; dt < 5; ++dt)
      AO[(size_t)row * HID + h * HD + dt * 16 + la] = f2bf(acc[dt][r] * inv);
  }
}

extern "C" void kernel_launch(void* const* d_in, const int* in_sizes, int n_in,
                              void* d_out, int out_size, void* d_ws, size_t ws_size,
                              hipStream_t stream) {
  const int* pos = (const int*)d_in[0];
  const void* hidden = d_in[1];   // [2048,2560] f32 or bf16
  const void* w_qkv = d_in[2];    // [2560,7680] f32 or bf16
  const void* w_out = d_in[3];    // [2560,2560] f32 or bf16
  u16* ws = (u16*)d_ws;

  // ws layout (u16 elements); WtQ region is dead after GEMM1 and is reused.
  u16* Hb = ws;                                  //  5,242,880
  u16* WtQ = Hb + (size_t)S_LEN * HID;           // 19,660,800
  u16* WtO = WtQ + (size_t)N3 * HID;             //  6,553,600
  u16* qkv = WtO + (size_t)HID * HID;            // 15,728,640
  int* flag = (int*)(qkv + (size_t)S_LEN * N3);  // 1 int
  u16* Qh = WtQ;                                 //  6,291,456 (alias)
  u16* Kh = Qh + (size_t)NHEAD * S_LEN * HDP;    //  6,291,456 (alias)
  u16* AO = Kh + (size_t)NHEAD * S_LEN * HDP;    //  5,242,880 (alias)

  detect_dtype<<<1, 256, 0, stream>>>((const u32*)hidden, flag);
  convert_hidden<<<(S_LEN * HID / 4 + 255) / 256, 256, 0, stream>>>(hidden, Hb,
                                                                    S_LEN * HID / 4, flag);
  transpose_conv<<<dim3(N3 / 32, HID / 32), 256, 0, stream>>>(w_qkv, WtQ, HID, N3, flag);
  transpose_conv<<<dim3(HID / 32, HID / 32), 256, 0, stream>>>(w_out, WtO, HID, HID, flag);
  gemm_bt<<<dim3(N3 / 128, S_LEN / 128), 256, 0, stream>>>(Hb, WtQ, qkv, S_LEN, N3, HID,
                                                           nullptr);
  rope_prep<<<dim3(S_LEN, NHEAD / 4), 256, 0, stream>>>(qkv, pos, Qh, Kh);
  attn_fused<<<dim3(S_LEN / 64, NHEAD), 256, 0, stream>>>(Qh, Kh, qkv, pos, AO);
  gemm_bt<<<dim3(HID / 128, S_LEN / 128), 256, 0, stream>>>(AO, WtO, d_out, S_LEN, HID, HID,
                                                            flag);
}

// Round 4
// 603.139 us; speedup vs baseline: 1.1430x; 1.1430x over previous
//
#include <hip/hip_runtime.h>
#include <type_traits>
#include <utility>

typedef unsigned short u16;
typedef unsigned int u32;
typedef __attribute__((ext_vector_type(8))) short short8;
typedef __attribute__((ext_vector_type(8))) __bf16 bhalf8;
typedef __attribute__((ext_vector_type(4))) short short4v;
typedef __attribute__((ext_vector_type(4))) __bf16 bhalf4;
typedef __attribute__((ext_vector_type(4))) float f32x4;
typedef __attribute__((ext_vector_type(4))) unsigned short us4;

#define S_LEN 2048
#define NHEAD 32
#define HD 80
#define HDP 96
#define HID 2560
#define N3 7680
#define QK_SCALE 0.11180339887498949f  // 80^-0.5
#define LOG2E 1.4426950408889634f

// ---------- MFMA K=32 wrapper (hedge: builtin may take __bf16x8 or shortx8) ----------
template <typename T, typename = void> struct MfmaTakes : std::false_type {};
template <typename T>
struct MfmaTakes<T, std::void_t<decltype(__builtin_amdgcn_mfma_f32_16x16x32_bf16(
                       std::declval<T>(), std::declval<T>(), std::declval<f32x4>(), 0, 0, 0))>>
    : std::true_type {};

template <typename AB>
__device__ inline f32x4 mfma_raw(AB a, AB b, f32x4 c) {
  return __builtin_amdgcn_mfma_f32_16x16x32_bf16(a, b, c, 0, 0, 0);
}
using mfma_ab_t = std::conditional_t<MfmaTakes<bhalf8>::value, bhalf8, short8>;
__device__ inline f32x4 MFMA(short8 a, short8 b, f32x4 c) {
  return mfma_raw<mfma_ab_t>(__builtin_bit_cast(mfma_ab_t, a),
                             __builtin_bit_cast(mfma_ab_t, b), c);
}

// ---------- MFMA K=16 wrapper (16x16x16 bf16), with emulation fallback ----------
#if defined(__has_builtin)
#if __has_builtin(__builtin_amdgcn_mfma_f32_16x16x16bf16_1k)
#define MFMA16_RAW(a, b, c) __builtin_amdgcn_mfma_f32_16x16x16bf16_1k(a, b, c, 0, 0, 0)
#define HAVE_MFMA16 1
#elif __has_builtin(__builtin_amdgcn_mfma_f32_16x16x16_bf16)
#define MFMA16_RAW(a, b, c) __builtin_amdgcn_mfma_f32_16x16x16_bf16(a, b, c, 0, 0, 0)
#define HAVE_MFMA16 1
#endif
#endif

#ifdef HAVE_MFMA16
template <typename T, typename = void> struct M16Takes : std::false_type {};
template <typename T>
struct M16Takes<T, std::void_t<decltype(MFMA16_RAW(std::declval<T>(), std::declval<T>(),
                                                   std::declval<f32x4>()))>> : std::true_type {};
using m16_t = std::conditional_t<M16Takes<bhalf4>::value, bhalf4, short4v>;
__device__ inline f32x4 MFMA16(short4v a, short4v b, f32x4 c) {
  return MFMA16_RAW(__builtin_bit_cast(m16_t, a), __builtin_bit_cast(m16_t, b), c);
}
#else
// Emulate K=16 via K=32 MFMA with zero upper k-half in BOTH operands:
// K=32 layout k = quad*8+j; zeros at j>=4 in A and B -> sum over 16 valid k only.
__device__ inline f32x4 MFMA16(short4v a, short4v b, f32x4 c) {
  short8 a8 = {a[0], a[1], a[2], a[3], 0, 0, 0, 0};
  short8 b8 = {b[0], b[1], b[2], b[3], 0, 0, 0, 0};
  return MFMA(a8, b8, c);
}
#endif

__device__ inline float bf2f(u16 b) { return __uint_as_float(((u32)b) << 16); }
__device__ inline u16 f2bf(float f) {
  u32 u = __float_as_uint(f);
  u += 0x7fffu + ((u >> 16) & 1u);  // round-to-nearest-even
  return (u16)(u >> 16);
}

typedef __attribute__((address_space(1))) void as1_void;
typedef __attribute__((address_space(3))) void as3_void;

#if defined(__has_builtin)
#if __has_builtin(__builtin_amdgcn_global_load_lds)
#define HAVE_GLL 1
#endif
#endif

// Stage 16B/lane: global (per-lane addr) -> LDS (wave-uniform base + lane*16).
__device__ inline void stage16(const u16* g, u16* lds_base, int lane) {
#ifdef HAVE_GLL
  (void)lane;
  __builtin_amdgcn_global_load_lds((as1_void*)g, (as3_void*)lds_base, 16, 0, 0);
#else
  *(short8*)(lds_base + lane * 8) = *(const short8*)g;
#endif
}

// ---------- dtype detection: are the float tensors f32 or bf16 on device? ----------
__global__ __launch_bounds__(256) void detect_dtype(const u32* __restrict__ words,
                                                    int* __restrict__ flag) {
  __shared__ int red[256];
  int junk = 0;
  for (int i = threadIdx.x; i < 2048; i += 256) {
    u16 lo = (u16)(words[i] & 0xffffu);
    u32 e = (lo >> 7) & 0xffu;  // bf16 exponent field
    junk += (e >= 137u);        // |x| >= 1024, or NaN/Inf
  }
  red[threadIdx.x] = junk;
  __syncthreads();
  for (int s = 128; s > 0; s >>= 1) {
    if (threadIdx.x < s) red[threadIdx.x] += red[threadIdx.x + s];
    __syncthreads();
  }
  if (threadIdx.x == 0) flag[0] = (red[0] > 64) ? 1 : 0;  // 1 = f32, 0 = bf16
}

// ---------- hidden_states -> bf16 (contiguous) ----------
__global__ __launch_bounds__(256) void convert_hidden(const void* __restrict__ in,
                                                      u16* __restrict__ out, int n4,
                                                      const int* __restrict__ flagp) {
  const int f = *flagp;
  int i = blockIdx.x * 256 + threadIdx.x;
  if (i >= n4) return;
  if (f) {
    const float* inf = (const float*)in;
    us4 o;
#pragma unroll
    for (int j = 0; j < 4; ++j) o[j] = f2bf(inf[(size_t)i * 4 + j]);
    *(us4*)&out[(size_t)i * 4] = o;
  } else {
    *(us4*)&out[(size_t)i * 4] = *(const us4*)&((const u16*)in)[(size_t)i * 4];
  }
}

// ---------- transpose + convert: in [rows, cols] (f32 or bf16) -> out [cols, rows] bf16 ----------
__global__ __launch_bounds__(256) void transpose_conv(const void* __restrict__ in,
                                                      u16* __restrict__ out,
                                                      int rows, int cols,
                                                      const int* __restrict__ flagp) {
  __shared__ u16 tile[32][33];
  const int f = *flagp;
  int bx = blockIdx.x * 32;  // col base
  int by = blockIdx.y * 32;  // row base
  int tx = threadIdx.x & 31, ty = threadIdx.x >> 5;
#pragma unroll
  for (int i = ty; i < 32; i += 8) {
    size_t idx = (size_t)(by + i) * cols + bx + tx;
    tile[i][tx] = f ? f2bf(((const float*)in)[idx]) : ((const u16*)in)[idx];
  }
  __syncthreads();
#pragma unroll
  for (int i = ty; i < 32; i += 8)
    out[(size_t)(bx + i) * rows + by + tx] = tile[tx][i];
}

// ---------- V transpose: qkv[s][5120 + c] -> Vt[c][s] (c = h*80+d) ----------
__global__ __launch_bounds__(256) void vtrans(const u16* __restrict__ qkv,
                                              u16* __restrict__ Vt) {
  __shared__ u16 tile[32][33];
  int bx = blockIdx.x * 32;  // col base (0..2560)
  int by = blockIdx.y * 32;  // s base
  int tx = threadIdx.x & 31, ty = threadIdx.x >> 5;
#pragma unroll
  for (int i = ty; i < 32; i += 8)
    tile[i][tx] = qkv[(size_t)(by + i) * N3 + 2 * HID + bx + tx];
  __syncthreads();
#pragma unroll
  for (int i = ty; i < 32; i += 8)
    Vt[(size_t)(bx + i) * S_LEN + by + tx] = tile[tx][i];
}

// ---------- GEMM: A[M,K] bf16 * Bt[N,K] bf16 -> C[M,N] (fp32 accum) ----------
__global__ __launch_bounds__(256) void gemm_bt(const u16* __restrict__ A,
                                               const u16* __restrict__ Bt,
                                               void* __restrict__ C,
                                               int M, int N, int K,
                                               const int* __restrict__ flagp) {
  __shared__ u16 As[128 * 32];
  __shared__ u16 Bs[128 * 32];
  const int tid = threadIdx.x;
  const int w = tid >> 6, l = tid & 63;
  const int la = l & 15, qd = l >> 4;
  const int m0 = blockIdx.y * 128, n0 = blockIdx.x * 128;
  const int mw = (w >> 1) * 64, nw = (w & 1) * 64;
  const int rowA = l >> 2;
  const int segk = (l & 3) * 8;
  const int of32 = flagp ? *flagp : 0;
  f32x4 acc[4][4] = {};

  for (int k0 = 0; k0 < K; k0 += 32) {
#pragma unroll
    for (int j = 0; j < 2; ++j) {
      const int rb = w * 16 + j * 64;
      const u16* ga = A + (size_t)(m0 + rb + rowA) * K + k0 + segk;
      const u16* gb = Bt + (size_t)(n0 + rb + rowA) * K + k0 + segk;
      stage16(ga, &As[rb * 32], l);
      stage16(gb, &Bs[rb * 32], l);
    }
    __syncthreads();
    short8 af[4], bfr[4];
#pragma unroll
    for (int i = 0; i < 4; ++i)
      af[i] = *(const short8*)&As[(mw + i * 16 + la) * 32 + qd * 8];
#pragma unroll
    for (int j = 0; j < 4; ++j)
      bfr[j] = *(const short8*)&Bs[(nw + j * 16 + la) * 32 + qd * 8];
#pragma unroll
    for (int i = 0; i < 4; ++i)
#pragma unroll
      for (int j = 0; j < 4; ++j)
        acc[i][j] = MFMA(af[i], bfr[j], acc[i][j]);
    __syncthreads();
  }

#pragma unroll
  for (int i = 0; i < 4; ++i)
#pragma unroll
    for (int j = 0; j < 4; ++j) {
      const int r0 = m0 + mw + i * 16 + qd * 4;
      const int c0 = n0 + nw + j * 16 + la;
#pragma unroll
      for (int r = 0; r < 4; ++r) {
        if (of32)
          ((float*)C)[(size_t)(r0 + r) * N + c0] = acc[i][j][r];
        else
          ((u16*)C)[(size_t)(r0 + r) * N + c0] = f2bf(acc[i][j][r]);
      }
    }
}

// ---------- RoPE prep: qkv[S,7680] -> Qh/Kh [NH][S][96] (bf16, zero-padded) ----------
__global__ __launch_bounds__(256) void rope_prep(const u16* __restrict__ qkv,
                                                 const int* __restrict__ pos,
                                                 u16* __restrict__ Qh,
                                                 u16* __restrict__ Kh) {
  const int s = blockIdx.x;
  const int h = blockIdx.y * 4 + (threadIdx.x >> 6);
  const int t = threadIdx.x & 63;
  const size_t qin = (size_t)s * N3 + h * HD;
  const size_t kin = qin + HID;
  const size_t ob = ((size_t)h * S_LEN + s) * HDP;
  if (t < 32) {
    const float p = (float)pos[s];
    const float inv = exp2f(-(float)t * (13.287712379549449f / 32.0f));
    const float ang = p * inv;
    const float cs = cosf(ang), sn = sinf(ang);
    float x1 = bf2f(qkv[qin + t]), x2 = bf2f(qkv[qin + t + 32]);
    Qh[ob + t] = f2bf(x1 * cs - x2 * sn);
    Qh[ob + t + 32] = f2bf(x2 * cs + x1 * sn);
    x1 = bf2f(qkv[kin + t]);
    x2 = bf2f(qkv[kin + t + 32]);
    Kh[ob + t] = f2bf(x1 * cs - x2 * sn);
    Kh[ob + t + 32] = f2bf(x2 * cs + x1 * sn);
  } else if (t < 48) {
    const int d = t + 32;  // 64..79 pass-through
    Qh[ob + d] = qkv[qin + d];
    Kh[ob + d] = qkv[kin + d];
  } else {
    const int d = t + 32;  // 80..95 zero pad
    Qh[ob + d] = 0;
    Kh[ob + d] = 0;
  }
}

// ---------- Fused causal+ALiBi flash attention (S^T orientation, no LDS) ----------
// Block = (head, 128 q rows); 4 independent waves x 32 q rows (2 subtiles of 16).
// S^T = K*Q^T via 16x16x32 MFMA; scores land as col=q,row=key -> the 4 C-regs per
// 16-key tile ARE the B-fragment of a 16x16x16 PV MFMA. No P LDS round-trip.
__global__ __launch_bounds__(256) void attn_fused(const u16* __restrict__ Qh,
                                                  const u16* __restrict__ Kh,
                                                  const u16* __restrict__ Vt,
                                                  u16* __restrict__ AO) {
  const int tid = threadIdx.x, w = tid >> 6, l = tid & 63;
  const int la = l & 15, qd = l >> 4;
  const int h = blockIdx.y;
  const int q0 = (int)(gridDim.x - 1 - blockIdx.x) * 128;  // longest-work-first
  const int qb = q0 + w * 32;
  const size_t hS = (size_t)h * S_LEN;

  short8 qf[2][3];
#pragma unroll
  for (int sq = 0; sq < 2; ++sq)
#pragma unroll
    for (int c = 0; c < 3; ++c)
      qf[sq][c] = *(const short8*)&Qh[(hS + qb + sq * 16 + la) * HDP + c * 32 + qd * 8];

  const float slope2 = exp2f(-0.25f * (float)(h + 1)) * LOG2E;
  const float scl2 = QK_SCALE * LOG2E;
  float m_i[2] = {-1e30f, -1e30f}, l_i[2] = {0.f, 0.f};
  f32x4 acc[2][5] = {};
  const int kend = qb + 32;  // causal: max key needed = max q in this wave

  for (int k0 = 0; k0 < kend; k0 += 64) {
    // --- S^T tiles: st[sq][kt] covers keys k0+kt*16.. x q subtile sq ---
    f32x4 st[2][4];
#pragma unroll
    for (int kt = 0; kt < 4; ++kt) {
      short8 kf[3];
#pragma unroll
      for (int c = 0; c < 3; ++c)
        kf[c] = *(const short8*)&Kh[(hS + k0 + kt * 16 + la) * HDP + c * 32 + qd * 8];
#pragma unroll
      for (int sq = 0; sq < 2; ++sq) {
        f32x4 z = {};
#pragma unroll
        for (int c = 0; c < 3; ++c) z = MFMA(kf[c], qf[sq][c], z);
        st[sq][kt] = z;
      }
    }
    // --- softmax (log2 domain), P packed to bf16 B-fragments in-register ---
    short4v pf[2][4];
#pragma unroll
    for (int sq = 0; sq < 2; ++sq) {
      const int q = qb + sq * 16 + la;
      float mloc = -1e30f;
#pragma unroll
      for (int kt = 0; kt < 4; ++kt)
#pragma unroll
        for (int r = 0; r < 4; ++r) {
          const int key = k0 + kt * 16 + qd * 4 + r;
          const float rel = (float)(key - q);
          const float v = (key <= q) ? st[sq][kt][r] * scl2 + slope2 * rel : -1e30f;
          st[sq][kt][r] = v;
          mloc = fmaxf(mloc, v);
        }
      mloc = fmaxf(mloc, __shfl_xor(mloc, 16));
      mloc = fmaxf(mloc, __shfl_xor(mloc, 32));
      const float nm = fmaxf(m_i[sq], mloc);
      const float al = exp2f(m_i[sq] - nm);
      m_i[sq] = nm;
      float ps = 0.f;
#pragma unroll
      for (int kt = 0; kt < 4; ++kt) {
        short4v pk;
#pragma unroll
        for (int r = 0; r < 4; ++r) {
          const float p = exp2f(st[sq][kt][r] - nm);
          ps += p;
          pk[r] = (short)f2bf(p);
        }
        pf[sq][kt] = pk;
      }
      ps += __shfl_xor(ps, 16);
      ps += __shfl_xor(ps, 32);
      l_i[sq] = l_i[sq] * al + ps;
#pragma unroll
      for (int dt = 0; dt < 5; ++dt) acc[sq][dt] *= al;
    }
    // --- PV: O^T[d][q] += V^T-frag (A) * P^T-frag (B), K=16 ---
#pragma unroll
    for (int dt = 0; dt < 5; ++dt) {
      const u16* vb = &Vt[(size_t)(h * HD + dt * 16 + la) * S_LEN + k0 + qd * 4];
#pragma unroll
      for (int kt = 0; kt < 4; ++kt) {
        const short4v vf = *(const short4v*)(vb + kt * 16);
#pragma unroll
        for (int sq = 0; sq < 2; ++sq)
          acc[sq][dt] = MFMA16(vf, pf[sq][kt], acc[sq][dt]);
      }
    }
  }

  // epilogue: lane holds O^T[d = dt*16+qd*4+r][q = qb+sq*16+la]
#pragma unroll
  for (int sq = 0; sq < 2; ++sq) {
    const float inv = 1.0f / l_i[sq];
    const size_t row = (size_t)(qb + sq * 16 + la);
#pragma unroll
    for (int dt = 0; dt < 5; ++dt)
#pragma unroll
      for (int r = 0; r < 4; ++r)
        AO[row * HID + h * HD + dt * 16 + qd * 4 + r] = f2bf(acc[sq][dt][r] * inv);
  }
}

extern "C" void kernel_launch(void* const* d_in, const int* in_sizes, int n_in,
                              void* d_out, int out_size, void* d_ws, size_t ws_size,
                              hipStream_t stream) {
  const int* pos = (const int*)d_in[0];
  const void* hidden = d_in[1];
  const void* w_qkv = d_in[2];
  const void* w_out = d_in[3];
  u16* ws = (u16*)d_ws;

  // ws layout (u16 elements). Hb dead after GEMM1 -> Vt aliases it (same size).
  // WtQ dead after GEMM1 -> Qh/Kh/AO alias into it (17.8M <= 19.66M).
  u16* Hb = ws;                                  //  5,242,880
  u16* WtQ = Hb + (size_t)S_LEN * HID;           // 19,660,800
  u16* WtO = WtQ + (size_t)N3 * HID;             //  6,553,600
  u16* qkv = WtO + (size_t)HID * HID;            // 15,728,640
  int* flag = (int*)(qkv + (size_t)S_LEN * N3);  // 1 int
  u16* Vt = Hb;                                  //  5,242,880 (alias)
  u16* Qh = WtQ;                                 //  6,291,456 (alias)
  u16* Kh = Qh + (size_t)NHEAD * S_LEN * HDP;    //  6,291,456 (alias)
  u16* AO = Kh + (size_t)NHEAD * S_LEN * HDP;    //  5,242,880 (alias)

  detect_dtype<<<1, 256, 0, stream>>>((const u32*)hidden, flag);
  convert_hidden<<<(S_LEN * HID / 4 + 255) / 256, 256, 0, stream>>>(hidden, Hb,
                                                                    S_LEN * HID / 4, flag);
  transpose_conv<<<dim3(N3 / 32, HID / 32), 256, 0, stream>>>(w_qkv, WtQ, HID, N3, flag);
  transpose_conv<<<dim3(HID / 32, HID / 32), 256, 0, stream>>>(w_out, WtO, HID, HID, flag);
  gemm_bt<<<dim3(N3 / 128, S_LEN / 128), 256, 0, stream>>>(Hb, WtQ, qkv, S_LEN, N3, HID,
                                                           nullptr);
  vtrans<<<dim3(HID / 32, S_LEN / 32), 256, 0, stream>>>(qkv, Vt);
  rope_prep<<<dim3(S_LEN, NHEAD / 4), 256, 0, stream>>>(qkv, pos, Qh, Kh);
  attn_fused<<<dim3(S_LEN / 128, NHEAD), 256, 0, stream>>>(Qh, Kh, Vt, AO);
  gemm_bt<<<dim3(HID / 128, S_LEN / 128), 256, 0, stream>>>(AO, WtO, d_out, S_LEN, HID, HID,
                                                            flag);
}

// Round 5
// 554.064 us; speedup vs baseline: 1.2442x; 1.0886x over previous
//
#include <hip/hip_runtime.h>
#include <type_traits>
#include <utility>

typedef unsigned short u16;
typedef unsigned int u32;
typedef __attribute__((ext_vector_type(8))) short short8;
typedef __attribute__((ext_vector_type(8))) __bf16 bhalf8;
typedef __attribute__((ext_vector_type(4))) short short4v;
typedef __attribute__((ext_vector_type(4))) __bf16 bhalf4;
typedef __attribute__((ext_vector_type(4))) float f32x4;
typedef __attribute__((ext_vector_type(4))) unsigned short us4;

#define S_LEN 2048
#define NHEAD 32
#define HD 80
#define HDP 96
#define HID 2560
#define N3 7680
#define QK_SCALE 0.11180339887498949f  // 80^-0.5
#define LOG2E 1.4426950408889634f

// ---------- MFMA K=32 wrapper (hedge: builtin may take __bf16x8 or shortx8) ----------
template <typename T, typename = void> struct MfmaTakes : std::false_type {};
template <typename T>
struct MfmaTakes<T, std::void_t<decltype(__builtin_amdgcn_mfma_f32_16x16x32_bf16(
                       std::declval<T>(), std::declval<T>(), std::declval<f32x4>(), 0, 0, 0))>>
    : std::true_type {};

template <typename AB>
__device__ inline f32x4 mfma_raw(AB a, AB b, f32x4 c) {
  return __builtin_amdgcn_mfma_f32_16x16x32_bf16(a, b, c, 0, 0, 0);
}
using mfma_ab_t = std::conditional_t<MfmaTakes<bhalf8>::value, bhalf8, short8>;
__device__ inline f32x4 MFMA(short8 a, short8 b, f32x4 c) {
  return mfma_raw<mfma_ab_t>(__builtin_bit_cast(mfma_ab_t, a),
                             __builtin_bit_cast(mfma_ab_t, b), c);
}

// ---------- MFMA K=16 wrapper (16x16x16 bf16), with emulation fallback ----------
#if defined(__has_builtin)
#if __has_builtin(__builtin_amdgcn_mfma_f32_16x16x16bf16_1k)
#define MFMA16_RAW(a, b, c) __builtin_amdgcn_mfma_f32_16x16x16bf16_1k(a, b, c, 0, 0, 0)
#define HAVE_MFMA16 1
#elif __has_builtin(__builtin_amdgcn_mfma_f32_16x16x16_bf16)
#define MFMA16_RAW(a, b, c) __builtin_amdgcn_mfma_f32_16x16x16_bf16(a, b, c, 0, 0, 0)
#define HAVE_MFMA16 1
#endif
#endif

#ifdef HAVE_MFMA16
template <typename T, typename = void> struct M16Takes : std::false_type {};
template <typename T>
struct M16Takes<T, std::void_t<decltype(MFMA16_RAW(std::declval<T>(), std::declval<T>(),
                                                   std::declval<f32x4>()))>> : std::true_type {};
using m16_t = std::conditional_t<M16Takes<bhalf4>::value, bhalf4, short4v>;
__device__ inline f32x4 MFMA16(short4v a, short4v b, f32x4 c) {
  return MFMA16_RAW(__builtin_bit_cast(m16_t, a), __builtin_bit_cast(m16_t, b), c);
}
#else
// Emulate K=16 via K=32 MFMA with zero upper k-half in BOTH operands.
__device__ inline f32x4 MFMA16(short4v a, short4v b, f32x4 c) {
  short8 a8 = {a[0], a[1], a[2], a[3], 0, 0, 0, 0};
  short8 b8 = {b[0], b[1], b[2], b[3], 0, 0, 0, 0};
  return MFMA(a8, b8, c);
}
#endif

__device__ inline float bf2f(u16 b) { return __uint_as_float(((u32)b) << 16); }
__device__ inline u16 f2bf(float f) {
  u32 u = __float_as_uint(f);
  u += 0x7fffu + ((u >> 16) & 1u);  // round-to-nearest-even
  return (u16)(u >> 16);
}

typedef __attribute__((address_space(1))) void as1_void;
typedef __attribute__((address_space(3))) void as3_void;

#if defined(__has_builtin)
#if __has_builtin(__builtin_amdgcn_global_load_lds)
#define HAVE_GLL 1
#endif
#endif

// Stage 16B/lane: global (per-lane addr) -> LDS (wave-uniform base + lane*16).
__device__ inline void stage16(const u16* g, u16* lds_base, int lane) {
#ifdef HAVE_GLL
  (void)lane;
  __builtin_amdgcn_global_load_lds((as1_void*)g, (as3_void*)lds_base, 16, 0, 0);
#else
  *(short8*)(lds_base + lane * 8) = *(const short8*)g;
#endif
}

// ---------- dtype detection: are the float tensors f32 or bf16 on device? ----------
__global__ __launch_bounds__(256) void detect_dtype(const u32* __restrict__ words,
                                                    int* __restrict__ flag) {
  __shared__ int red[256];
  int junk = 0;
  for (int i = threadIdx.x; i < 2048; i += 256) {
    u16 lo = (u16)(words[i] & 0xffffu);
    u32 e = (lo >> 7) & 0xffu;  // bf16 exponent field
    junk += (e >= 137u);        // |x| >= 1024, or NaN/Inf
  }
  red[threadIdx.x] = junk;
  __syncthreads();
  for (int s = 128; s > 0; s >>= 1) {
    if (threadIdx.x < s) red[threadIdx.x] += red[threadIdx.x + s];
    __syncthreads();
  }
  if (threadIdx.x == 0) flag[0] = (red[0] > 64) ? 1 : 0;  // 1 = f32, 0 = bf16
}

// ---------- hidden_states -> bf16 (contiguous) ----------
__global__ __launch_bounds__(256) void convert_hidden(const void* __restrict__ in,
                                                      u16* __restrict__ out, int n4,
                                                      const int* __restrict__ flagp) {
  const int f = *flagp;
  int i = blockIdx.x * 256 + threadIdx.x;
  if (i >= n4) return;
  if (f) {
    const float* inf = (const float*)in;
    us4 o;
#pragma unroll
    for (int j = 0; j < 4; ++j) o[j] = f2bf(inf[(size_t)i * 4 + j]);
    *(us4*)&out[(size_t)i * 4] = o;
  } else {
    *(us4*)&out[(size_t)i * 4] = *(const us4*)&((const u16*)in)[(size_t)i * 4];
  }
}

// ---------- transpose + convert: in [rows, cols] (f32 or bf16) -> out [cols, rows] bf16 ----------
__global__ __launch_bounds__(256) void transpose_conv(const void* __restrict__ in,
                                                      u16* __restrict__ out,
                                                      int rows, int cols,
                                                      const int* __restrict__ flagp) {
  __shared__ u16 tile[32][33];
  const int f = *flagp;
  int bx = blockIdx.x * 32;  // col base
  int by = blockIdx.y * 32;  // row base
  int tx = threadIdx.x & 31, ty = threadIdx.x >> 5;
#pragma unroll
  for (int i = ty; i < 32; i += 8) {
    size_t idx = (size_t)(by + i) * cols + bx + tx;
    tile[i][tx] = f ? f2bf(((const float*)in)[idx]) : ((const u16*)in)[idx];
  }
  __syncthreads();
#pragma unroll
  for (int i = ty; i < 32; i += 8)
    out[(size_t)(bx + i) * rows + by + tx] = tile[tx][i];
}

// ---------- V transpose: qkv[s][5120 + c] -> Vt[c][s] (c = h*80+d) ----------
__global__ __launch_bounds__(256) void vtrans(const u16* __restrict__ qkv,
                                              u16* __restrict__ Vt) {
  __shared__ u16 tile[32][33];
  int bx = blockIdx.x * 32;  // col base (0..2560)
  int by = blockIdx.y * 32;  // s base
  int tx = threadIdx.x & 31, ty = threadIdx.x >> 5;
#pragma unroll
  for (int i = ty; i < 32; i += 8)
    tile[i][tx] = qkv[(size_t)(by + i) * N3 + 2 * HID + bx + tx];
  __syncthreads();
#pragma unroll
  for (int i = ty; i < 32; i += 8)
    Vt[(size_t)(bx + i) * S_LEN + by + tx] = tile[tx][i];
}

// ---------- GEMM: A[M,K] bf16 * Bt[N,K] bf16 -> C[M,N] (fp32 accum) ----------
__global__ __launch_bounds__(256) void gemm_bt(const u16* __restrict__ A,
                                               const u16* __restrict__ Bt,
                                               void* __restrict__ C,
                                               int M, int N, int K,
                                               const int* __restrict__ flagp) {
  __shared__ u16 As[128 * 32];
  __shared__ u16 Bs[128 * 32];
  const int tid = threadIdx.x;
  const int w = tid >> 6, l = tid & 63;
  const int la = l & 15, qd = l >> 4;
  const int m0 = blockIdx.y * 128, n0 = blockIdx.x * 128;
  const int mw = (w >> 1) * 64, nw = (w & 1) * 64;
  const int rowA = l >> 2;
  const int segk = (l & 3) * 8;
  const int of32 = flagp ? *flagp : 0;
  f32x4 acc[4][4] = {};

  for (int k0 = 0; k0 < K; k0 += 32) {
#pragma unroll
    for (int j = 0; j < 2; ++j) {
      const int rb = w * 16 + j * 64;
      const u16* ga = A + (size_t)(m0 + rb + rowA) * K + k0 + segk;
      const u16* gb = Bt + (size_t)(n0 + rb + rowA) * K + k0 + segk;
      stage16(ga, &As[rb * 32], l);
      stage16(gb, &Bs[rb * 32], l);
    }
    __syncthreads();
    short8 af[4], bfr[4];
#pragma unroll
    for (int i = 0; i < 4; ++i)
      af[i] = *(const short8*)&As[(mw + i * 16 + la) * 32 + qd * 8];
#pragma unroll
    for (int j = 0; j < 4; ++j)
      bfr[j] = *(const short8*)&Bs[(nw + j * 16 + la) * 32 + qd * 8];
#pragma unroll
    for (int i = 0; i < 4; ++i)
#pragma unroll
      for (int j = 0; j < 4; ++j)
        acc[i][j] = MFMA(af[i], bfr[j], acc[i][j]);
    __syncthreads();
  }

#pragma unroll
  for (int i = 0; i < 4; ++i)
#pragma unroll
    for (int j = 0; j < 4; ++j) {
      const int r0 = m0 + mw + i * 16 + qd * 4;
      const int c0 = n0 + nw + j * 16 + la;
#pragma unroll
      for (int r = 0; r < 4; ++r) {
        if (of32)
          ((float*)C)[(size_t)(r0 + r) * N + c0] = acc[i][j][r];
        else
          ((u16*)C)[(size_t)(r0 + r) * N + c0] = f2bf(acc[i][j][r]);
      }
    }
}

// ---------- RoPE prep: qkv[S,7680] -> Qh/Kh [NH][S][96] (bf16, zero-padded) ----------
__global__ __launch_bounds__(256) void rope_prep(const u16* __restrict__ qkv,
                                                 const int* __restrict__ pos,
                                                 u16* __restrict__ Qh,
                                                 u16* __restrict__ Kh) {
  const int s = blockIdx.x;
  const int h = blockIdx.y * 4 + (threadIdx.x >> 6);
  const int t = threadIdx.x & 63;
  const size_t qin = (size_t)s * N3 + h * HD;
  const size_t kin = qin + HID;
  const size_t ob = ((size_t)h * S_LEN + s) * HDP;
  if (t < 32) {
    const float p = (float)pos[s];
    const float inv = exp2f(-(float)t * (13.287712379549449f / 32.0f));
    const float ang = p * inv;
    const float cs = cosf(ang), sn = sinf(ang);
    float x1 = bf2f(qkv[qin + t]), x2 = bf2f(qkv[qin + t + 32]);
    Qh[ob + t] = f2bf(x1 * cs - x2 * sn);
    Qh[ob + t + 32] = f2bf(x2 * cs + x1 * sn);
    x1 = bf2f(qkv[kin + t]);
    x2 = bf2f(qkv[kin + t + 32]);
    Kh[ob + t] = f2bf(x1 * cs - x2 * sn);
    Kh[ob + t + 32] = f2bf(x2 * cs + x1 * sn);
  } else if (t < 48) {
    const int d = t + 32;  // 64..79 pass-through
    Qh[ob + d] = qkv[qin + d];
    Kh[ob + d] = qkv[kin + d];
  } else {
    const int d = t + 32;  // 80..95 zero pad
    Qh[ob + d] = 0;
    Kh[ob + d] = 0;
  }
}

// ---------- Fused causal+ALiBi flash attention (S^T orientation, LDS-shared K/V) ----------
// Block = (head, 128 q rows); 4 waves x 32 q rows (2 subtiles of 16).
// Per 64-key iteration: K tile (64x96) staged via global_load_lds (linear, coalesced),
// V^T tile (80x64) staged via vector-load + ds_write into stride-72 rows (pad kills
// the 16-way bank conflict an unpadded 64-stride would cause on the b64 frag reads).
// S^T = K*Q^T; score C-regs are directly the B-fragment of the 16x16x16 PV MFMA.
__global__ __launch_bounds__(256) void attn_fused(const u16* __restrict__ Qh,
                                                  const u16* __restrict__ Kh,
                                                  const u16* __restrict__ Vt,
                                                  u16* __restrict__ AO) {
  __shared__ u16 Ks[64 * HDP];  // 64 keys x 96 dims, row-contiguous (12288 B)
  __shared__ u16 Vs[HD * 72];   // 80 d-rows x (64 keys + 8 pad)   (11520 B)
  const int tid = threadIdx.x, w = tid >> 6, l = tid & 63;
  const int la = l & 15, qd = l >> 4;
  const int h = blockIdx.y;
  const int q0 = (int)(gridDim.x - 1 - blockIdx.x) * 128;  // longest-work-first
  const int qb = q0 + w * 32;
  const size_t hS = (size_t)h * S_LEN;

  short8 qf[2][3];
#pragma unroll
  for (int sq = 0; sq < 2; ++sq)
#pragma unroll
    for (int c = 0; c < 3; ++c)
      qf[sq][c] = *(const short8*)&Qh[(hS + qb + sq * 16 + la) * HDP + c * 32 + qd * 8];

  const float slope2 = exp2f(-0.25f * (float)(h + 1)) * LOG2E;
  const float scl2 = QK_SCALE * LOG2E;
  float m_i[2] = {-1e30f, -1e30f}, l_i[2] = {0.f, 0.f};
  f32x4 acc[2][5] = {};
  const int kend = q0 + 128;  // block-uniform (barriers inside the loop)

  for (int k0 = 0; k0 < kend; k0 += 64) {
    // --- stage K tile: 12288 B linear via global_load_lds, 3 calls/thread ---
    const u16* gk = &Kh[(hS + k0) * HDP];
#pragma unroll
    for (int j = 0; j < 3; ++j) {
      const int c0 = j * 256 + w * 64;  // wave-uniform slab base (x16 B)
      stage16(gk + (size_t)(c0 + l) * 8, &Ks[(size_t)c0 * 8], l);
    }
    // --- stage V^T tile: 80 rows x 128 B, padded LDS rows (VGPR path) ---
    const u16* gv = &Vt[(size_t)h * HD * S_LEN + k0];
#pragma unroll
    for (int c = tid; c < 640; c += 256) {
      const int row = c >> 3, seg = c & 7;
      *(short8*)&Vs[row * 72 + seg * 8] =
          *(const short8*)(gv + (size_t)row * S_LEN + seg * 8);
    }
    __syncthreads();  // drains vmcnt (global_load_lds) + lgkmcnt (ds_write)

    if (k0 < qb + 32) {  // skip fully-masked tiles (barrier still honored)
      // --- S^T tiles from LDS ---
      f32x4 st[2][4];
#pragma unroll
      for (int kt = 0; kt < 4; ++kt) {
        short8 kf[3];
#pragma unroll
        for (int c = 0; c < 3; ++c)
          kf[c] = *(const short8*)&Ks[(kt * 16 + la) * HDP + c * 32 + qd * 8];
#pragma unroll
        for (int sq = 0; sq < 2; ++sq) {
          f32x4 z = {};
#pragma unroll
          for (int c = 0; c < 3; ++c) z = MFMA(kf[c], qf[sq][c], z);
          st[sq][kt] = z;
        }
      }
      // --- softmax (log2 domain), P packed to bf16 B-fragments in-register ---
      short4v pf[2][4];
#pragma unroll
      for (int sq = 0; sq < 2; ++sq) {
        const int q = qb + sq * 16 + la;
        float mloc = -1e30f;
#pragma unroll
        for (int kt = 0; kt < 4; ++kt)
#pragma unroll
          for (int r = 0; r < 4; ++r) {
            const int key = k0 + kt * 16 + qd * 4 + r;
            const float rel = (float)(key - q);
            const float v = (key <= q) ? st[sq][kt][r] * scl2 + slope2 * rel : -1e30f;
            st[sq][kt][r] = v;
            mloc = fmaxf(mloc, v);
          }
        mloc = fmaxf(mloc, __shfl_xor(mloc, 16));
        mloc = fmaxf(mloc, __shfl_xor(mloc, 32));
        const float nm = fmaxf(m_i[sq], mloc);
        const float al = exp2f(m_i[sq] - nm);
        m_i[sq] = nm;
        float ps = 0.f;
#pragma unroll
        for (int kt = 0; kt < 4; ++kt) {
          short4v pk;
#pragma unroll
          for (int r = 0; r < 4; ++r) {
            const float p = exp2f(st[sq][kt][r] - nm);
            ps += p;
            pk[r] = (short)f2bf(p);
          }
          pf[sq][kt] = pk;
        }
        ps += __shfl_xor(ps, 16);
        ps += __shfl_xor(ps, 32);
        l_i[sq] = l_i[sq] * al + ps;
#pragma unroll
        for (int dt = 0; dt < 5; ++dt) acc[sq][dt] *= al;
      }
      // --- PV from LDS: O^T[d][q] += V^T-frag (A) * P^T-frag (B), K=16 ---
#pragma unroll
      for (int dt = 0; dt < 5; ++dt) {
#pragma unroll
        for (int kt = 0; kt < 4; ++kt) {
          const short4v vf = *(const short4v*)&Vs[(dt * 16 + la) * 72 + kt * 16 + qd * 4];
#pragma unroll
          for (int sq = 0; sq < 2; ++sq)
            acc[sq][dt] = MFMA16(vf, pf[sq][kt], acc[sq][dt]);
        }
      }
    }
    __syncthreads();  // protect LDS before next overwrite
  }

  // epilogue: lane holds O^T[d = dt*16+qd*4+r][q = qb+sq*16+la]; 8B stores
#pragma unroll
  for (int sq = 0; sq < 2; ++sq) {
    const float inv = 1.0f / l_i[sq];
    const size_t row = (size_t)(qb + sq * 16 + la);
#pragma unroll
    for (int dt = 0; dt < 5; ++dt) {
      us4 o;
#pragma unroll
      for (int r = 0; r < 4; ++r) o[r] = f2bf(acc[sq][dt][r] * inv);
      *(us4*)&AO[row * HID + h * HD + dt * 16 + qd * 4] = o;
    }
  }
}

extern "C" void kernel_launch(void* const* d_in, const int* in_sizes, int n_in,
                              void* d_out, int out_size, void* d_ws, size_t ws_size,
                              hipStream_t stream) {
  const int* pos = (const int*)d_in[0];
  const void* hidden = d_in[1];
  const void* w_qkv = d_in[2];
  const void* w_out = d_in[3];
  u16* ws = (u16*)d_ws;

  // ws layout (u16 elements). Hb dead after GEMM1 -> Vt aliases it (same size).
  // WtQ dead after GEMM1 -> Qh/Kh/AO alias into it (17.8M <= 19.66M).
  u16* Hb = ws;                                  //  5,242,880
  u16* WtQ = Hb + (size_t)S_LEN * HID;           // 19,660,800
  u16* WtO = WtQ + (size_t)N3 * HID;             //  6,553,600
  u16* qkv = WtO + (size_t)HID * HID;            // 15,728,640
  int* flag = (int*)(qkv + (size_t)S_LEN * N3);  // 1 int
  u16* Vt = Hb;                                  //  5,242,880 (alias)
  u16* Qh = WtQ;                                 //  6,291,456 (alias)
  u16* Kh = Qh + (size_t)NHEAD * S_LEN * HDP;    //  6,291,456 (alias)
  u16* AO = Kh + (size_t)NHEAD * S_LEN * HDP;    //  5,242,880 (alias)

  detect_dtype<<<1, 256, 0, stream>>>((const u32*)hidden, flag);
  convert_hidden<<<(S_LEN * HID / 4 + 255) / 256, 256, 0, stream>>>(hidden, Hb,
                                                                    S_LEN * HID / 4, flag);
  transpose_conv<<<dim3(N3 / 32, HID / 32), 256, 0, stream>>>(w_qkv, WtQ, HID, N3, flag);
  transpose_conv<<<dim3(HID / 32, HID / 32), 256, 0, stream>>>(w_out, WtO, HID, HID, flag);
  gemm_bt<<<dim3(N3 / 128, S_LEN / 128), 256, 0, stream>>>(Hb, WtQ, qkv, S_LEN, N3, HID,
                                                           nullptr);
  vtrans<<<dim3(HID / 32, S_LEN / 32), 256, 0, stream>>>(qkv, Vt);
  rope_prep<<<dim3(S_LEN, NHEAD / 4), 256, 0, stream>>>(qkv, pos, Qh, Kh);
  attn_fused<<<dim3(S_LEN / 128, NHEAD), 256, 0, stream>>>(Qh, Kh, Vt, AO);
  gemm_bt<<<dim3(HID / 128, S_LEN / 128), 256, 0, stream>>>(AO, WtO, d_out, S_LEN, HID, HID,
                                                            flag);
}

// Round 6
// 541.326 us; speedup vs baseline: 1.2735x; 1.0235x over previous
//
#include <hip/hip_runtime.h>
#include <type_traits>
#include <utility>

typedef unsigned short u16;
typedef unsigned int u32;
typedef __attribute__((ext_vector_type(8))) short short8;
typedef __attribute__((ext_vector_type(8))) __bf16 bhalf8;
typedef __attribute__((ext_vector_type(4))) short short4v;
typedef __attribute__((ext_vector_type(4))) __bf16 bhalf4;
typedef __attribute__((ext_vector_type(4))) float f32x4;
typedef __attribute__((ext_vector_type(4))) unsigned short us4;

#define S_LEN 2048
#define NHEAD 32
#define HD 80
#define HDP 96
#define HID 2560
#define N3 7680
#define QK_SCALE 0.11180339887498949f  // 80^-0.5
#define LOG2E 1.4426950408889634f

// ---------- MFMA K=32 wrapper (hedge: builtin may take __bf16x8 or shortx8) ----------
template <typename T, typename = void> struct MfmaTakes : std::false_type {};
template <typename T>
struct MfmaTakes<T, std::void_t<decltype(__builtin_amdgcn_mfma_f32_16x16x32_bf16(
                       std::declval<T>(), std::declval<T>(), std::declval<f32x4>(), 0, 0, 0))>>
    : std::true_type {};

template <typename AB>
__device__ inline f32x4 mfma_raw(AB a, AB b, f32x4 c) {
  return __builtin_amdgcn_mfma_f32_16x16x32_bf16(a, b, c, 0, 0, 0);
}
using mfma_ab_t = std::conditional_t<MfmaTakes<bhalf8>::value, bhalf8, short8>;
__device__ inline f32x4 MFMA(short8 a, short8 b, f32x4 c) {
  return mfma_raw<mfma_ab_t>(__builtin_bit_cast(mfma_ab_t, a),
                             __builtin_bit_cast(mfma_ab_t, b), c);
}

// ---------- MFMA K=16 wrapper (16x16x16 bf16), with emulation fallback ----------
#if defined(__has_builtin)
#if __has_builtin(__builtin_amdgcn_mfma_f32_16x16x16bf16_1k)
#define MFMA16_RAW(a, b, c) __builtin_amdgcn_mfma_f32_16x16x16bf16_1k(a, b, c, 0, 0, 0)
#define HAVE_MFMA16 1
#elif __has_builtin(__builtin_amdgcn_mfma_f32_16x16x16_bf16)
#define MFMA16_RAW(a, b, c) __builtin_amdgcn_mfma_f32_16x16x16_bf16(a, b, c, 0, 0, 0)
#define HAVE_MFMA16 1
#endif
#endif

#ifdef HAVE_MFMA16
template <typename T, typename = void> struct M16Takes : std::false_type {};
template <typename T>
struct M16Takes<T, std::void_t<decltype(MFMA16_RAW(std::declval<T>(), std::declval<T>(),
                                                   std::declval<f32x4>()))>> : std::true_type {};
using m16_t = std::conditional_t<M16Takes<bhalf4>::value, bhalf4, short4v>;
__device__ inline f32x4 MFMA16(short4v a, short4v b, f32x4 c) {
  return MFMA16_RAW(__builtin_bit_cast(m16_t, a), __builtin_bit_cast(m16_t, b), c);
}
#else
// Emulate K=16 via K=32 MFMA with zero upper k-half in BOTH operands.
__device__ inline f32x4 MFMA16(short4v a, short4v b, f32x4 c) {
  short8 a8 = {a[0], a[1], a[2], a[3], 0, 0, 0, 0};
  short8 b8 = {b[0], b[1], b[2], b[3], 0, 0, 0, 0};
  return MFMA(a8, b8, c);
}
#endif

__device__ inline float bf2f(u16 b) { return __uint_as_float(((u32)b) << 16); }
__device__ inline u16 f2bf(float f) {
  u32 u = __float_as_uint(f);
  u += 0x7fffu + ((u >> 16) & 1u);  // round-to-nearest-even
  return (u16)(u >> 16);
}

typedef __attribute__((address_space(1))) void as1_void;
typedef __attribute__((address_space(3))) void as3_void;

#if defined(__has_builtin)
#if __has_builtin(__builtin_amdgcn_global_load_lds)
#define HAVE_GLL 1
#endif
#endif

// Stage 16B/lane: global (per-lane addr) -> LDS (wave-uniform base + lane*16).
__device__ inline void stage16(const u16* g, u16* lds_base, int lane) {
#ifdef HAVE_GLL
  (void)lane;
  __builtin_amdgcn_global_load_lds((as1_void*)g, (as3_void*)lds_base, 16, 0, 0);
#else
  *(short8*)(lds_base + lane * 8) = *(const short8*)g;
#endif
}

// ---------- dtype detection: are the float tensors f32 or bf16 on device? ----------
__global__ __launch_bounds__(256) void detect_dtype(const u32* __restrict__ words,
                                                    int* __restrict__ flag) {
  __shared__ int red[256];
  int junk = 0;
  for (int i = threadIdx.x; i < 2048; i += 256) {
    u16 lo = (u16)(words[i] & 0xffffu);
    u32 e = (lo >> 7) & 0xffu;  // bf16 exponent field
    junk += (e >= 137u);        // |x| >= 1024, or NaN/Inf
  }
  red[threadIdx.x] = junk;
  __syncthreads();
  for (int s = 128; s > 0; s >>= 1) {
    if (threadIdx.x < s) red[threadIdx.x] += red[threadIdx.x + s];
    __syncthreads();
  }
  if (threadIdx.x == 0) flag[0] = (red[0] > 64) ? 1 : 0;  // 1 = f32, 0 = bf16
}

// ---------- hidden_states -> bf16 (contiguous) ----------
__global__ __launch_bounds__(256) void convert_hidden(const void* __restrict__ in,
                                                      u16* __restrict__ out, int n4,
                                                      const int* __restrict__ flagp) {
  const int f = *flagp;
  int i = blockIdx.x * 256 + threadIdx.x;
  if (i >= n4) return;
  if (f) {
    const float* inf = (const float*)in;
    us4 o;
#pragma unroll
    for (int j = 0; j < 4; ++j) o[j] = f2bf(inf[(size_t)i * 4 + j]);
    *(us4*)&out[(size_t)i * 4] = o;
  } else {
    *(us4*)&out[(size_t)i * 4] = *(const us4*)&((const u16*)in)[(size_t)i * 4];
  }
}

// ---------- transpose + convert: in [rows, cols] (f32 or bf16) -> out [cols, rows] bf16 ----------
__global__ __launch_bounds__(256) void transpose_conv(const void* __restrict__ in,
                                                      u16* __restrict__ out,
                                                      int rows, int cols,
                                                      const int* __restrict__ flagp) {
  __shared__ u16 tile[32][33];
  const int f = *flagp;
  int bx = blockIdx.x * 32;  // col base
  int by = blockIdx.y * 32;  // row base
  int tx = threadIdx.x & 31, ty = threadIdx.x >> 5;
#pragma unroll
  for (int i = ty; i < 32; i += 8) {
    size_t idx = (size_t)(by + i) * cols + bx + tx;
    tile[i][tx] = f ? f2bf(((const float*)in)[idx]) : ((const u16*)in)[idx];
  }
  __syncthreads();
#pragma unroll
  for (int i = ty; i < 32; i += 8)
    out[(size_t)(bx + i) * rows + by + tx] = tile[tx][i];
}

// ---------- V transpose: qkv[s][5120 + c] -> Vt[c][s] (c = h*80+d) ----------
__global__ __launch_bounds__(256) void vtrans(const u16* __restrict__ qkv,
                                              u16* __restrict__ Vt) {
  __shared__ u16 tile[32][33];
  int bx = blockIdx.x * 32;  // col base (0..2560)
  int by = blockIdx.y * 32;  // s base
  int tx = threadIdx.x & 31, ty = threadIdx.x >> 5;
#pragma unroll
  for (int i = ty; i < 32; i += 8)
    tile[i][tx] = qkv[(size_t)(by + i) * N3 + 2 * HID + bx + tx];
  __syncthreads();
#pragma unroll
  for (int i = ty; i < 32; i += 8)
    Vt[(size_t)(bx + i) * S_LEN + by + tx] = tile[tx][i];
}

// ---------- GEMM: A[M,K] bf16 * Bt[N,K] bf16 -> C[M,N] (fp32 accum) ----------
__global__ __launch_bounds__(256) void gemm_bt(const u16* __restrict__ A,
                                               const u16* __restrict__ Bt,
                                               void* __restrict__ C,
                                               int M, int N, int K,
                                               const int* __restrict__ flagp) {
  __shared__ u16 As[128 * 32];
  __shared__ u16 Bs[128 * 32];
  const int tid = threadIdx.x;
  const int w = tid >> 6, l = tid & 63;
  const int la = l & 15, qd = l >> 4;
  const int m0 = blockIdx.y * 128, n0 = blockIdx.x * 128;
  const int mw = (w >> 1) * 64, nw = (w & 1) * 64;
  const int rowA = l >> 2;
  const int segk = (l & 3) * 8;
  const int of32 = flagp ? *flagp : 0;
  f32x4 acc[4][4] = {};

  for (int k0 = 0; k0 < K; k0 += 32) {
#pragma unroll
    for (int j = 0; j < 2; ++j) {
      const int rb = w * 16 + j * 64;
      const u16* ga = A + (size_t)(m0 + rb + rowA) * K + k0 + segk;
      const u16* gb = Bt + (size_t)(n0 + rb + rowA) * K + k0 + segk;
      stage16(ga, &As[rb * 32], l);
      stage16(gb, &Bs[rb * 32], l);
    }
    __syncthreads();
    short8 af[4], bfr[4];
#pragma unroll
    for (int i = 0; i < 4; ++i)
      af[i] = *(const short8*)&As[(mw + i * 16 + la) * 32 + qd * 8];
#pragma unroll
    for (int j = 0; j < 4; ++j)
      bfr[j] = *(const short8*)&Bs[(nw + j * 16 + la) * 32 + qd * 8];
#pragma unroll
    for (int i = 0; i < 4; ++i)
#pragma unroll
      for (int j = 0; j < 4; ++j)
        acc[i][j] = MFMA(af[i], bfr[j], acc[i][j]);
    __syncthreads();
  }

#pragma unroll
  for (int i = 0; i < 4; ++i)
#pragma unroll
    for (int j = 0; j < 4; ++j) {
      const int r0 = m0 + mw + i * 16 + qd * 4;
      const int c0 = n0 + nw + j * 16 + la;
#pragma unroll
      for (int r = 0; r < 4; ++r) {
        if (of32)
          ((float*)C)[(size_t)(r0 + r) * N + c0] = acc[i][j][r];
        else
          ((u16*)C)[(size_t)(r0 + r) * N + c0] = f2bf(acc[i][j][r]);
      }
    }
}

// ---------- RoPE prep: qkv[S,7680] -> Qh/Kh [NH][S][96] (bf16, zero-padded) ----------
__global__ __launch_bounds__(256) void rope_prep(const u16* __restrict__ qkv,
                                                 const int* __restrict__ pos,
                                                 u16* __restrict__ Qh,
                                                 u16* __restrict__ Kh) {
  const int s = blockIdx.x;
  const int h = blockIdx.y * 4 + (threadIdx.x >> 6);
  const int t = threadIdx.x & 63;
  const size_t qin = (size_t)s * N3 + h * HD;
  const size_t kin = qin + HID;
  const size_t ob = ((size_t)h * S_LEN + s) * HDP;
  if (t < 32) {
    const float p = (float)pos[s];
    const float inv = exp2f(-(float)t * (13.287712379549449f / 32.0f));
    const float ang = p * inv;
    const float cs = cosf(ang), sn = sinf(ang);
    float x1 = bf2f(qkv[qin + t]), x2 = bf2f(qkv[qin + t + 32]);
    Qh[ob + t] = f2bf(x1 * cs - x2 * sn);
    Qh[ob + t + 32] = f2bf(x2 * cs + x1 * sn);
    x1 = bf2f(qkv[kin + t]);
    x2 = bf2f(qkv[kin + t + 32]);
    Kh[ob + t] = f2bf(x1 * cs - x2 * sn);
    Kh[ob + t + 32] = f2bf(x2 * cs + x1 * sn);
  } else if (t < 48) {
    const int d = t + 32;  // 64..79 pass-through
    Qh[ob + d] = qkv[qin + d];
    Kh[ob + d] = qkv[kin + d];
  } else {
    const int d = t + 32;  // 80..95 zero pad
    Qh[ob + d] = 0;
    Kh[ob + d] = 0;
  }
}

// ---------- Fused causal+ALiBi flash attention ----------
// Block = (head, 128 q rows); 4 waves x 32 q rows (2 subtiles of 16).
// Double-buffered LDS K/V tiles, ALL staging via global_load_lds (fire-and-forget),
// one barrier per iteration: barrier -> issue prefetch(it+1) -> compute(it).
// V tile stored with XOR column swizzle col' = (k + (row&7)*8) & 63 so that the
// ds_read_b64 fragment reads are bank-conflict-free without padding (gll needs
// lane-linear LDS, but the GLOBAL address is per-lane -> swizzle on the read side
// of global memory instead of the write side of LDS).
__global__ __launch_bounds__(256) void attn_fused(const u16* __restrict__ Qh,
                                                  const u16* __restrict__ Kh,
                                                  const u16* __restrict__ Vt,
                                                  u16* __restrict__ AO) {
  __shared__ u16 Ks[2][64 * HDP];  // 2 x 12288 B
  __shared__ u16 Vs[2][HD * 64];   // 2 x 10240 B (swizzled columns)
  const int tid = threadIdx.x, w = tid >> 6, l = tid & 63;
  const int la = l & 15, qd = l >> 4;
  const int h = blockIdx.y;
  const int q0 = (int)(gridDim.x - 1 - blockIdx.x) * 128;  // longest-work-first
  const int qb = q0 + w * 32;
  const size_t hS = (size_t)h * S_LEN;
  const int niter = (q0 + 128) >> 6;

  short8 qf[2][3];
#pragma unroll
  for (int sq = 0; sq < 2; ++sq)
#pragma unroll
    for (int c = 0; c < 3; ++c)
      qf[sq][c] = *(const short8*)&Qh[(hS + qb + sq * 16 + la) * HDP + c * 32 + qd * 8];

  const float slope2 = exp2f(-0.25f * (float)(h + 1)) * LOG2E;
  const float scl2 = QK_SCALE * LOG2E;
  float m_i[2] = {-1e30f, -1e30f}, l_i[2] = {0.f, 0.f};
  f32x4 acc[2][5] = {};

  const u16* gK = &Kh[hS * HDP];
  const u16* gV = &Vt[(size_t)h * HD * S_LEN];

  // Issue (async) staging of the 64-key tile at k0 into buffer `buf`.
  auto stage = [&](int k0, int buf) {
    const u16* gk = gK + (size_t)k0 * HDP;
#pragma unroll
    for (int j = 0; j < 3; ++j) {  // 768 chunks of 16 B (64 rows x 96)
      const int c0 = j * 256 + w * 64;
      stage16(gk + (size_t)(c0 + l) * 8, &Ks[buf][c0 * 8], l);
    }
    const u16* gv = gV + k0;
#pragma unroll
    for (int j = 0; j < 3; ++j) {  // 640 chunks of 16 B (80 rows x 64)
      const int c0 = j * 256 + w * 64;
      if (c0 < 640) {  // wave-uniform guard
        const int c = c0 + l;
        const int row = c >> 3, seg = c & 7;
        const int gcol = ((seg - (row & 7)) & 7) * 8;  // inverse of col swizzle
        stage16(gv + (size_t)row * S_LEN + gcol, &Vs[buf][c0 * 8], l);
      }
    }
  };

  stage(0, 0);
  for (int it = 0; it < niter; ++it) {
    const int k0 = it << 6;
    const int buf = it & 1;
    __syncthreads();  // stage(it) complete; all waves done with buf^1
    if (it + 1 < niter) stage(k0 + 64, buf ^ 1);  // prefetch, hidden by compute

    if (k0 < qb + 32) {  // wave-uniform skip of fully-masked tiles
      // --- S^T tiles from LDS ---
      f32x4 st[2][4];
#pragma unroll
      for (int kt = 0; kt < 4; ++kt) {
        short8 kf[3];
#pragma unroll
        for (int c = 0; c < 3; ++c)
          kf[c] = *(const short8*)&Ks[buf][(kt * 16 + la) * HDP + c * 32 + qd * 8];
#pragma unroll
        for (int sq = 0; sq < 2; ++sq) {
          f32x4 z = {};
#pragma unroll
          for (int c = 0; c < 3; ++c) z = MFMA(kf[c], qf[sq][c], z);
          st[sq][kt] = z;
        }
      }
      // --- softmax (log2 domain), P packed to bf16 B-fragments in-register ---
      short4v pf[2][4];
#pragma unroll
      for (int sq = 0; sq < 2; ++sq) {
        const int q = qb + sq * 16 + la;
        float mloc = -1e30f;
#pragma unroll
        for (int kt = 0; kt < 4; ++kt)
#pragma unroll
          for (int r = 0; r < 4; ++r) {
            const int key = k0 + kt * 16 + qd * 4 + r;
            const float rel = (float)(key - q);
            const float v = (key <= q) ? st[sq][kt][r] * scl2 + slope2 * rel : -1e30f;
            st[sq][kt][r] = v;
            mloc = fmaxf(mloc, v);
          }
        mloc = fmaxf(mloc, __shfl_xor(mloc, 16));
        mloc = fmaxf(mloc, __shfl_xor(mloc, 32));
        const float nm = fmaxf(m_i[sq], mloc);
        const float al = exp2f(m_i[sq] - nm);
        m_i[sq] = nm;
        float ps = 0.f;
#pragma unroll
        for (int kt = 0; kt < 4; ++kt) {
          short4v pk;
#pragma unroll
          for (int r = 0; r < 4; ++r) {
            const float p = exp2f(st[sq][kt][r] - nm);
            ps += p;
            pk[r] = (short)f2bf(p);
          }
          pf[sq][kt] = pk;
        }
        ps += __shfl_xor(ps, 16);
        ps += __shfl_xor(ps, 32);
        l_i[sq] = l_i[sq] * al + ps;
#pragma unroll
        for (int dt = 0; dt < 5; ++dt) acc[sq][dt] *= al;
      }
      // --- PV from LDS (swizzled, conflict-free b64): O^T += V^T * P^T, K=16 ---
      const int cb = qd * 4 + ((la & 7) << 3);
#pragma unroll
      for (int dt = 0; dt < 5; ++dt) {
        const int vrow = (dt * 16 + la) * 64;
#pragma unroll
        for (int kt = 0; kt < 4; ++kt) {
          const short4v vf = *(const short4v*)&Vs[buf][vrow + ((kt * 16 + cb) & 63)];
#pragma unroll
          for (int sq = 0; sq < 2; ++sq)
            acc[sq][dt] = MFMA16(vf, pf[sq][kt], acc[sq][dt]);
        }
      }
    }
  }

  // epilogue: lane holds O^T[d = dt*16+qd*4+r][q = qb+sq*16+la]; 8B stores
#pragma unroll
  for (int sq = 0; sq < 2; ++sq) {
    const float inv = 1.0f / l_i[sq];
    const size_t row = (size_t)(qb + sq * 16 + la);
#pragma unroll
    for (int dt = 0; dt < 5; ++dt) {
      us4 o;
#pragma unroll
      for (int r = 0; r < 4; ++r) o[r] = f2bf(acc[sq][dt][r] * inv);
      *(us4*)&AO[row * HID + h * HD + dt * 16 + qd * 4] = o;
    }
  }
}

extern "C" void kernel_launch(void* const* d_in, const int* in_sizes, int n_in,
                              void* d_out, int out_size, void* d_ws, size_t ws_size,
                              hipStream_t stream) {
  const int* pos = (const int*)d_in[0];
  const void* hidden = d_in[1];
  const void* w_qkv = d_in[2];
  const void* w_out = d_in[3];
  u16* ws = (u16*)d_ws;

  // ws layout (u16 elements). Hb dead after GEMM1 -> Vt aliases it (same size).
  // WtQ dead after GEMM1 -> Qh/Kh/AO alias into it (17.8M <= 19.66M).
  u16* Hb = ws;                                  //  5,242,880
  u16* WtQ = Hb + (size_t)S_LEN * HID;           // 19,660,800
  u16* WtO = WtQ + (size_t)N3 * HID;             //  6,553,600
  u16* qkv = WtO + (size_t)HID * HID;            // 15,728,640
  int* flag = (int*)(qkv + (size_t)S_LEN * N3);  // 1 int
  u16* Vt = Hb;                                  //  5,242,880 (alias)
  u16* Qh = WtQ;                                 //  6,291,456 (alias)
  u16* Kh = Qh + (size_t)NHEAD * S_LEN * HDP;    //  6,291,456 (alias)
  u16* AO = Kh + (size_t)NHEAD * S_LEN * HDP;    //  5,242,880 (alias)

  detect_dtype<<<1, 256, 0, stream>>>((const u32*)hidden, flag);
  convert_hidden<<<(S_LEN * HID / 4 + 255) / 256, 256, 0, stream>>>(hidden, Hb,
                                                                    S_LEN * HID / 4, flag);
  transpose_conv<<<dim3(N3 / 32, HID / 32), 256, 0, stream>>>(w_qkv, WtQ, HID, N3, flag);
  transpose_conv<<<dim3(HID / 32, HID / 32), 256, 0, stream>>>(w_out, WtO, HID, HID, flag);
  gemm_bt<<<dim3(N3 / 128, S_LEN / 128), 256, 0, stream>>>(Hb, WtQ, qkv, S_LEN, N3, HID,
                                                           nullptr);
  vtrans<<<dim3(HID / 32, S_LEN / 32), 256, 0, stream>>>(qkv, Vt);
  rope_prep<<<dim3(S_LEN, NHEAD / 4), 256, 0, stream>>>(qkv, pos, Qh, Kh);
  attn_fused<<<dim3(S_LEN / 128, NHEAD), 256, 0, stream>>>(Qh, Kh, Vt, AO);
  gemm_bt<<<dim3(HID / 128, S_LEN / 128), 256, 0, stream>>>(AO, WtO, d_out, S_LEN, HID, HID,
                                                            flag);
}